// Round 1
// baseline (288.718 us; speedup 1.0000x reference)
//
#include <hip/hip_runtime.h>

// Problem constants (from reference setup_inputs)
constexpr int B  = 4096;    // batch rows
constexpr int D  = 784;     // feature dim
constexpr int O1 = 8192;    // 2-term products
constexpr int O2 = 8192;    // 3-term products
constexpr int OT = O1 + O2; // 16384 output cols per row

constexpr int TPB  = 256;
constexpr int ROWS = 4;     // rows per block; matches float4 (ds_read_b128) exactly
constexpr int VEC  = 4;     // cols per thread per group (float4 store)
constexpr int CPB  = 2048;  // cols per block; 8192%2048==0 so a block never
                            // straddles the out1/out2 boundary
constexpr int GROUPS = CPB / (TPB * VEC); // 2

// Index-major LDS: xs4[d] = {x[row0+0][d], x[row0+1][d], x[row0+2][d], x[row0+3][d]}.
// One ds_read_b128 per gather index serves ALL 4 rows -> 4x fewer LDS
// instructions than xs[ROWS][D] with per-row ds_read_b32.
// launch_bounds (256,4): 128 VGPR cap (3-term path holds 12 float4 gather
// results live), 16 waves/CU — enough TLP for a store-streaming kernel.
__global__ __launch_bounds__(TPB, 4) void randomde_kernel(
    const float* __restrict__ x,
    const int*   __restrict__ idx1,
    const int*   __restrict__ idx2,
    float*       __restrict__ out)
{
    __shared__ float4 xs4[D];   // 784 * 16 B = 12544 B

    const int tid     = threadIdx.x;
    const int row0    = blockIdx.y * ROWS;
    const int colBase = blockIdx.x * CPB;

    // Stage transposed: per d, 4 coalesced scalar loads (one per row) + one
    // ds_write_b128 at byte 16*d. Lane i touches banks 4i..4i+3 mod 32 ->
    // exactly 8 lanes/bank, conflict-free in the 2-way-free sense.
    for (int d = tid; d < D; d += TPB) {
        float4 v;
        v.x = x[(size_t)(row0 + 0) * D + d];
        v.y = x[(size_t)(row0 + 1) * D + d];
        v.z = x[(size_t)(row0 + 2) * D + d];
        v.w = x[(size_t)(row0 + 3) * D + d];
        xs4[d] = v;
    }
    __syncthreads();

    const int c0 = colBase + tid * VEC;      // group 0 column; group 1 = c0 + TPB*VEC

    if (colBase < O1) {
        // ---- 2-term region: idx for 4 cols = 2 int4 (32B aligned) ----
        #pragma unroll
        for (int g = 0; g < GROUPS; ++g) {
            const int c = c0 + g * TPB * VEC;
            const int4* __restrict__ ip = (const int4*)(idx1 + (size_t)c * 2);
            const int4 i0 = ip[0], i1 = ip[1];
            // 8 b128 gathers cover 4 cols x 4 rows
            const float4 qa = xs4[i0.x], qb = xs4[i0.y];
            const float4 qc = xs4[i0.z], qd = xs4[i0.w];
            const float4 qe = xs4[i1.x], qf = xs4[i1.y];
            const float4 qg = xs4[i1.z], qh = xs4[i1.w];
            #pragma unroll
            for (int r = 0; r < ROWS; ++r) {   // r is literal after unroll -> SROA to regs
                float4 v;
                v.x = ((const float*)&qa)[r] * ((const float*)&qb)[r];
                v.y = ((const float*)&qc)[r] * ((const float*)&qd)[r];
                v.z = ((const float*)&qe)[r] * ((const float*)&qf)[r];
                v.w = ((const float*)&qg)[r] * ((const float*)&qh)[r];
                *(float4*)(out + (size_t)(row0 + r) * OT + c) = v;
            }
        }
    } else {
        // ---- 3-term region: idx for 4 cols = 3 int4 (16B aligned) ----
        #pragma unroll
        for (int g = 0; g < GROUPS; ++g) {
            const int c = c0 + g * TPB * VEC;
            const int4* __restrict__ ip = (const int4*)(idx2 + (size_t)(c - O1) * 3);
            const int4 i0 = ip[0], i1 = ip[1], i2 = ip[2];
            // 12 b128 gathers cover 4 cols x 4 rows
            const float4 q0 = xs4[i0.x], q1 = xs4[i0.y], q2 = xs4[i0.z];
            const float4 q3 = xs4[i0.w], q4 = xs4[i1.x], q5 = xs4[i1.y];
            const float4 q6 = xs4[i1.z], q7 = xs4[i1.w], q8 = xs4[i2.x];
            const float4 q9 = xs4[i2.y], qA = xs4[i2.z], qB = xs4[i2.w];
            #pragma unroll
            for (int r = 0; r < ROWS; ++r) {
                float4 v;
                // left-assoc product order matches jnp.prod (absmax must stay 0)
                v.x = ((const float*)&q0)[r] * ((const float*)&q1)[r] * ((const float*)&q2)[r];
                v.y = ((const float*)&q3)[r] * ((const float*)&q4)[r] * ((const float*)&q5)[r];
                v.z = ((const float*)&q6)[r] * ((const float*)&q7)[r] * ((const float*)&q8)[r];
                v.w = ((const float*)&q9)[r] * ((const float*)&qA)[r] * ((const float*)&qB)[r];
                *(float4*)(out + (size_t)(row0 + r) * OT + c) = v;
            }
        }
    }
}

extern "C" void kernel_launch(void* const* d_in, const int* in_sizes, int n_in,
                              void* d_out, int out_size, void* d_ws, size_t ws_size,
                              hipStream_t stream) {
    const float* x    = (const float*)d_in[0];
    const int*   idx1 = (const int*)d_in[1];
    const int*   idx2 = (const int*)d_in[2];
    float*       out  = (float*)d_out;

    dim3 grid(OT / CPB, B / ROWS);  // (8, 1024) = 8192 blocks
    dim3 block(TPB);
    randomde_kernel<<<grid, block, 0, stream>>>(x, idx1, idx2, out);
}

// Round 3
// 279.863 us; speedup vs baseline: 1.0316x; 1.0316x over previous
//
#include <hip/hip_runtime.h>

// Problem constants (from reference setup_inputs)
constexpr int B  = 4096;    // batch rows
constexpr int D  = 784;     // feature dim
constexpr int O1 = 8192;    // 2-term products
constexpr int O2 = 8192;    // 3-term products
constexpr int OT = O1 + O2; // 16384 output cols per row

constexpr int TPB  = 256;
constexpr int ROWS = 4;     // rows per block; matches float4 (ds_read_b128) exactly
constexpr int VEC  = 4;     // cols per thread per group (float4 store)
constexpr int CPB  = 8192;  // cols per block = one FULL region (all 2-term or all
                            // 3-term) -> staging re-reads /4, branch is grid-static
constexpr int GROUPS = CPB / (TPB * VEC); // 8

// Native clang vector type: __builtin_nontemporal_store requires a real vector
// type, not HIP_vector_type<float,4> (which is a struct).
typedef float f32x4 __attribute__((ext_vector_type(4)));

// Index-major LDS: xs4[d] = {x[row0+0][d], .., x[row0+3][d]}; one ds_read_b128
// per gather index serves all 4 rows.
// Output is write-once, never re-read -> nontemporal stores keep 268 MB of
// streaming writes from churning L2 (which x/idx staging wants resident).
__global__ __launch_bounds__(TPB, 4) void randomde_kernel(
    const float* __restrict__ x,
    const int*   __restrict__ idx1,
    const int*   __restrict__ idx2,
    float*       __restrict__ out)
{
    __shared__ f32x4 xs4[D];   // 784 * 16 B = 12544 B

    const int tid  = threadIdx.x;
    const int row0 = blockIdx.y * ROWS;

    // Stage transposed: per d, 4 coalesced scalar loads (one per row) + one
    // ds_write_b128 at byte 16*d (8 lanes/bank, conflict-free).
    for (int d = tid; d < D; d += TPB) {
        f32x4 v;
        v.x = x[(size_t)(row0 + 0) * D + d];
        v.y = x[(size_t)(row0 + 1) * D + d];
        v.z = x[(size_t)(row0 + 2) * D + d];
        v.w = x[(size_t)(row0 + 3) * D + d];
        xs4[d] = v;
    }
    __syncthreads();

    const int c0 = blockIdx.x * CPB + tid * VEC;

    if (blockIdx.x == 0) {
        // ---- 2-term region (cols [0, 8192)) ----
        #pragma unroll
        for (int g = 0; g < GROUPS; ++g) {
            const int c = c0 + g * TPB * VEC;
            const int4* __restrict__ ip = (const int4*)(idx1 + (size_t)c * 2);
            const int4 i0 = ip[0], i1 = ip[1];
            // 8 b128 gathers cover 4 cols x 4 rows
            const f32x4 qa = xs4[i0.x], qb = xs4[i0.y];
            const f32x4 qc = xs4[i0.z], qd = xs4[i0.w];
            const f32x4 qe = xs4[i1.x], qf = xs4[i1.y];
            const f32x4 qg = xs4[i1.z], qh = xs4[i1.w];
            #pragma unroll
            for (int r = 0; r < ROWS; ++r) {   // r literal after unroll -> regs
                f32x4 v;
                v.x = qa[r] * qb[r];
                v.y = qc[r] * qd[r];
                v.z = qe[r] * qf[r];
                v.w = qg[r] * qh[r];
                __builtin_nontemporal_store(
                    v, (f32x4*)(out + (size_t)(row0 + r) * OT + c));
            }
        }
    } else {
        // ---- 3-term region (cols [8192, 16384)) ----
        #pragma unroll
        for (int g = 0; g < GROUPS; ++g) {
            const int c = c0 + g * TPB * VEC;
            const int4* __restrict__ ip = (const int4*)(idx2 + (size_t)(c - O1) * 3);
            const int4 i0 = ip[0], i1 = ip[1], i2 = ip[2];
            // 12 b128 gathers cover 4 cols x 4 rows
            const f32x4 q0 = xs4[i0.x], q1 = xs4[i0.y], q2 = xs4[i0.z];
            const f32x4 q3 = xs4[i0.w], q4 = xs4[i1.x], q5 = xs4[i1.y];
            const f32x4 q6 = xs4[i1.z], q7 = xs4[i1.w], q8 = xs4[i2.x];
            const f32x4 q9 = xs4[i2.y], qA = xs4[i2.z], qB = xs4[i2.w];
            #pragma unroll
            for (int r = 0; r < ROWS; ++r) {
                f32x4 v;
                // left-assoc product order matches jnp.prod (absmax must stay 0)
                v.x = q0[r] * q1[r] * q2[r];
                v.y = q3[r] * q4[r] * q5[r];
                v.z = q6[r] * q7[r] * q8[r];
                v.w = q9[r] * qA[r] * qB[r];
                __builtin_nontemporal_store(
                    v, (f32x4*)(out + (size_t)(row0 + r) * OT + c));
            }
        }
    }
}

extern "C" void kernel_launch(void* const* d_in, const int* in_sizes, int n_in,
                              void* d_out, int out_size, void* d_ws, size_t ws_size,
                              hipStream_t stream) {
    const float* x    = (const float*)d_in[0];
    const int*   idx1 = (const int*)d_in[1];
    const int*   idx2 = (const int*)d_in[2];
    float*       out  = (float*)d_out;

    dim3 grid(OT / CPB, B / ROWS);  // (2, 1024) = 2048 blocks
    dim3 block(TPB);
    randomde_kernel<<<grid, block, 0, stream>>>(x, idx1, idx2, out);
}